// Round 7
// baseline (365.400 us; speedup 1.0000x reference)
//
#include <hip/hip_runtime.h>
#include <hip/hip_bf16.h>

// GCN layer: out[c] = bias + dis[c]*(hs[c] + sum_{r in in(c)} hs[r]),
//            hs = (X @ W) * dis[row]  (bf16), dis = rsqrt(deg+1).
// N=50000, E=800000, D=64, fp32 in/out.
// R21: MEASUREMENT ROUND 2. Exact R16 kernels (gather reverted to scalar
//      wave-uniform form; R20's paired loads broke SGPR indexing, +9.4us),
//      with the four BUILD kernels wrapped in MREP=8 idempotent repetition
//      loops. Each kernel with t>5.5us surfaces in rocprof top-5 with its own
//      dur+counters (/8); dur decodes T4 = t_hist+t_reduce+t_gemm+t_bucket via
//      dur = 128.7 + 7*T4. With R19 (t_gather+gap=23.6) this pins gap too.
//      R22 reverts MREP and attacks the largest measured component.

constexpr int N_NODES = 50000;
constexpr int N_EDGES = 800000;
constexpr int D = 64;
constexpr int NB_SCAN = (N_NODES + 255) / 256;  // 196
constexpr int MREP = 8;                          // measurement repetition

constexpr int B_SLICE = 64;                  // edge slices
constexpr int SLICE = N_EDGES / B_SLICE;     // 12500 (exact)
constexpr int PACK8 = N_NODES / 4;           // 12500 u32 words (u8 x4)
constexpr int QUAR = N_NODES / 4;            // 12500 nodes per bucket quarter

static __device__ __forceinline__ unsigned short f2bf(float f) {
    unsigned u = __float_as_uint(f);
    unsigned r = (u + 0x7fffu + ((u >> 16) & 1u)) >> 16;  // RNE
    return (unsigned short)r;
}
static __device__ __forceinline__ float bf2f(unsigned short s) {
    return __uint_as_float((unsigned)s << 16);
}

// ---- 1. per-slice u8-packed histograms (R12 proven; x8 for measurement) ----
__global__ __launch_bounds__(1024) void hist_priv_kernel(const int* __restrict__ ei,
                                                         unsigned* __restrict__ bh) {
    __shared__ unsigned loc[PACK8];  // 50 KB
    int b = blockIdx.x;
    int s = b & (B_SLICE - 1);
    const int* arr = (b < B_SLICE) ? ei : ei + N_EDGES;
    const int* p = arr + s * SLICE;
    unsigned* dst = bh + (size_t)b * PACK8;
    for (int rep = 0; rep < MREP; ++rep) {
        __syncthreads();  // prior rep's dst writes read loc; guard re-zero
        for (int w = threadIdx.x; w < PACK8; w += 1024) loc[w] = 0;
        __syncthreads();
        for (int i = threadIdx.x; i < SLICE; i += 1024) {
            int k = p[i];
            atomicAdd(&loc[k >> 2], 1u << (8 * (k & 3)));  // LDS atomic
        }
        __syncthreads();
        for (int w = threadIdx.x; w < PACK8; w += 1024) dst[w] = loc[w];
    }
}

// ---- 2. reduce + dis + inline bs8 + block-local scan (R12; x8) ----
__global__ __launch_bounds__(256) void reduce_scan_kernel(const unsigned* __restrict__ bh,
                                                          float* __restrict__ dis,
                                                          int* __restrict__ offs_local,
                                                          int* __restrict__ partials,
                                                          unsigned char* __restrict__ bs8) {
    __shared__ int s[256];
    int t = threadIdx.x;
    int i = blockIdx.x * 256 + t;
    for (int rep = 0; rep < MREP; ++rep) {
        __syncthreads();
        unsigned cl = 0;
        if (i < N_NODES) {
            const int w = i >> 2;
            const unsigned sh = 8 * (i & 3);
            const unsigned* prow = bh + w;
            unsigned dl = 0;
#pragma unroll
            for (int g = 0; g < 4; ++g) {
                unsigned vr[16];
#pragma unroll
                for (int k = 0; k < 16; ++k) vr[k] = prow[(size_t)(g * 16 + k) * PACK8];
#pragma unroll
                for (int k = 0; k < 16; ++k) dl += (vr[k] >> sh) & 0xffu;
            }
            dis[i] = rsqrtf((float)dl + 1.0f);  // +1 self loop
            const unsigned* pcol = bh + (size_t)B_SLICE * PACK8 + w;
#pragma unroll
            for (int g = 0; g < 4; ++g) {
                unsigned vr[16];
#pragma unroll
                for (int k = 0; k < 16; ++k) vr[k] = pcol[(size_t)(g * 16 + k) * PACK8];
#pragma unroll
                for (int k = 0; k < 16; ++k) {
                    bs8[(size_t)(g * 16 + k) * N_NODES + i] = (unsigned char)cl;
                    cl += (vr[k] >> sh) & 0xffu;
                }
            }
        }
        s[t] = (int)cl;
        __syncthreads();
        for (int d = 1; d < 256; d <<= 1) {
            int u = (t >= d) ? s[t - d] : 0;
            __syncthreads();
            s[t] += u;
            __syncthreads();
        }
        if (i < N_NODES) offs_local[i] = s[t] - (int)cl;
        if (t == 255) partials[blockIdx.x] = s[t];
    }
}

// ---- 3. gemm + fused offs finalize (R12/R15 proven; x8) ----
__global__ __launch_bounds__(256, 4) void gemm_kernel(const float* __restrict__ x,
                                                      const float* __restrict__ W,
                                                      const float* __restrict__ dis,
                                                      unsigned short* __restrict__ hs,
                                                      const int* __restrict__ offs_local,
                                                      const int* __restrict__ partials,
                                                      int* __restrict__ offs,
                                                      int do_offs) {
    __shared__ float Xs[64][68];
    __shared__ float Ws[64][64];
    __shared__ int pref[256];
    int t = threadIdx.x;
    int b = blockIdx.x;

    for (int rep = 0; rep < MREP; ++rep) {
        __syncthreads();  // guard LDS overwrite vs prior rep reads
        if (do_offs && b < NB_SCAN) {
            pref[t] = (t < NB_SCAN) ? partials[t] : 0;
            __syncthreads();
            for (int d = 1; d < 256; d <<= 1) {
                int u = (t >= d) ? pref[t - d] : 0;
                __syncthreads();
                pref[t] += u;
                __syncthreads();
            }
            int base = pref[b] - partials[b];
            int node = b * 256 + t;
            if (node < N_NODES) offs[node] = base + offs_local[node];
            if (b == 0 && t == 0) offs[N_NODES] = N_EDGES;
        }

        int n0 = b * 64;
        const float4* W4 = (const float4*)W;
        float4* Ws4 = (float4*)Ws;
#pragma unroll
        for (int i = 0; i < 4; ++i) Ws4[t + i * 256] = W4[t + i * 256];

        const float4* x4 = (const float4*)(x + (size_t)n0 * D);
#pragma unroll
        for (int i = 0; i < 4; ++i) {
            int f = t + i * 256;
            int r = f >> 4, c = (f & 15) << 2;
            float4 v = make_float4(0.f, 0.f, 0.f, 0.f);
            if (n0 + r < N_NODES) v = x4[f];
            Xs[r][c] = v.x; Xs[r][c + 1] = v.y; Xs[r][c + 2] = v.z; Xs[r][c + 3] = v.w;
        }
        __syncthreads();

        int tx = t & 15, ty = t >> 4;
        float acc[4][4] = {};
#pragma unroll 8
        for (int k = 0; k < D; ++k) {
            float a[4], bb[4];
#pragma unroll
            for (int i = 0; i < 4; ++i) a[i] = Xs[ty * 4 + i][k];
#pragma unroll
            for (int jj = 0; jj < 4; ++jj) bb[jj] = Ws[k][tx * 4 + jj];
#pragma unroll
            for (int i = 0; i < 4; ++i)
#pragma unroll
                for (int jj = 0; jj < 4; ++jj)
                    acc[i][jj] = fmaf(a[i], bb[jj], acc[i][jj]);
        }

#pragma unroll
        for (int i = 0; i < 4; ++i) {
            int r = ty * 4 + i;
            if (n0 + r < N_NODES) {
                float dr = dis[n0 + r];
                ushort4 v;
                v.x = f2bf(acc[i][0] * dr); v.y = f2bf(acc[i][1] * dr);
                v.z = f2bf(acc[i][2] * dr); v.w = f2bf(acc[i][3] * dr);
                *(ushort4*)(hs + (size_t)(n0 + r) * D + tx * 4) = v;
            }
        }
    }
}

// ---- 4. bucket: u8-packed LDS position counters (R16 proven; x8) ----
__global__ __launch_bounds__(1024) void bucket_det_kernel(const int* __restrict__ ei,
                                                          const unsigned char* __restrict__ bs8,
                                                          const int* __restrict__ offs,
                                                          int* __restrict__ csr) {
    __shared__ unsigned pos[QUAR / 4];  // 12.5 KB, u8 x4 per word
    const int t = threadIdx.x;
    const int s = blockIdx.x >> 2;
    const int q = blockIdx.x & 3;
    const int c0 = q * QUAR;
    const unsigned* rel32 = (const unsigned*)(bs8 + (size_t)s * N_NODES + c0);
    const int* rowp = ei + s * SLICE;
    const int* colp = ei + N_EDGES + s * SLICE;

    for (int rep = 0; rep < MREP; ++rep) {
        __syncthreads();  // prior rep's atomics on pos done before re-init
        for (int w = t; w < QUAR / 4; w += 1024) pos[w] = rel32[w];
        __syncthreads();
        for (int i = t; i < SLICE; i += 1024) {
            int c = colp[i];
            unsigned cc = (unsigned)(c - c0);
            if (cc < (unsigned)QUAR) {
                int base = offs[c];
                unsigned old = atomicAdd(&pos[cc >> 2], 1u << (8 * (cc & 3)));
                unsigned rel = (old >> (8 * (cc & 3))) & 0xffu;
                csr[base + (int)rel] = rowp[i];
            }
        }
    }
}

// ---- 5. gather: wave per node, scalar csr loads, MLP 16 (R16 exact, x1) ----
__global__ __launch_bounds__(256) void gather_kernel(const int* __restrict__ offs,
                                                     const int* __restrict__ csr,
                                                     const unsigned short* __restrict__ hs,
                                                     const float* __restrict__ dis,
                                                     const float* __restrict__ bias,
                                                     float* __restrict__ out) {
    int wave = threadIdx.x >> 6;
    int j = threadIdx.x & 63;
    int n = blockIdx.x * 4 + wave;
    if (n >= N_NODES) return;

    float a[8];
    a[0] = bf2f(hs[(size_t)n * D + j]);  // self loop (dis[n]*h[n])
#pragma unroll
    for (int k = 1; k < 8; ++k) a[k] = 0.f;

    int beg = __builtin_amdgcn_readfirstlane(offs[n]);
    int m   = __builtin_amdgcn_readfirstlane(offs[n + 1]) - beg;
    const int* p = csr + beg;

    int i = 0;
    for (; i + 16 <= m; i += 16) {
        int r[16];
        float v[16];
#pragma unroll
        for (int k = 0; k < 16; ++k) r[k] = p[i + k];
#pragma unroll
        for (int k = 0; k < 16; ++k) v[k] = bf2f(hs[(size_t)r[k] * D + j]);
#pragma unroll
        for (int k = 0; k < 16; ++k) a[k & 7] += v[k];
    }
    for (; i + 4 <= m; i += 4) {
        int r0 = p[i], r1 = p[i + 1], r2 = p[i + 2], r3 = p[i + 3];
        a[0] += bf2f(hs[(size_t)r0 * D + j]);
        a[1] += bf2f(hs[(size_t)r1 * D + j]);
        a[2] += bf2f(hs[(size_t)r2 * D + j]);
        a[3] += bf2f(hs[(size_t)r3 * D + j]);
    }
    for (; i < m; ++i) a[1] += bf2f(hs[(size_t)p[i] * D + j]);
    float tot = ((a[0] + a[1]) + (a[2] + a[3])) + ((a[4] + a[5]) + (a[6] + a[7]));
    out[(size_t)n * D + j] = fmaf(dis[n], tot, bias[j]);
}

// ======================= fallback (atomic) build path =======================

__global__ void histf_kernel(const int* __restrict__ row, const int* __restrict__ col,
                             int* __restrict__ degi, int* __restrict__ cnt) {
    int e = blockIdx.x * blockDim.x + threadIdx.x;
    if (e < N_EDGES) {
        atomicAdd(&degi[row[e]], 1);
        atomicAdd(&cnt[col[e]], 1);
    }
}

__global__ void disf_kernel(int* __restrict__ degi) {
    int i = blockIdx.x * blockDim.x + threadIdx.x;
    if (i < N_NODES) {
        float d = (float)degi[i] + 1.0f;
        ((float*)degi)[i] = rsqrtf(d);
    }
}

__global__ void block_scan_kernel(const int* __restrict__ cnt, int* __restrict__ offs,
                                  int* __restrict__ partials) {
    __shared__ int s[256];
    int t = threadIdx.x;
    int i = blockIdx.x * 256 + t;
    int v = (i < N_NODES) ? cnt[i] : 0;
    s[t] = v;
    __syncthreads();
    for (int d = 1; d < 256; d <<= 1) {
        int u = (t >= d) ? s[t - d] : 0;
        __syncthreads();
        s[t] += u;
        __syncthreads();
    }
    if (i < N_NODES) offs[i] = s[t] - v;
    if (t == 255) partials[blockIdx.x] = s[t];
}

__global__ void scan_partials_kernel(int* __restrict__ partials) {
    __shared__ int s[256];
    int t = threadIdx.x;
    int v = (t < NB_SCAN) ? partials[t] : 0;
    s[t] = v;
    __syncthreads();
    for (int d = 1; d < 256; d <<= 1) {
        int u = (t >= d) ? s[t - d] : 0;
        __syncthreads();
        s[t] += u;
        __syncthreads();
    }
    if (t < NB_SCAN) partials[t] = s[t] - v;
}

__global__ void add_off_kernel(int* __restrict__ offs, const int* __restrict__ partials) {
    int i = blockIdx.x * 256 + threadIdx.x;
    if (i < N_NODES) offs[i] += partials[blockIdx.x];
    if (i == 0) offs[N_NODES] = N_EDGES;
}

__global__ void bucket_fb_kernel(const int* __restrict__ row, const int* __restrict__ col,
                                 const int* __restrict__ offs, int* __restrict__ cur,
                                 int* __restrict__ csr) {
    int e = blockIdx.x * blockDim.x + threadIdx.x;
    if (e < N_EDGES) {
        int c = col[e];
        int pos = offs[c] + atomicAdd(&cur[c], 1);
        csr[pos] = row[e];
    }
}

// ======================= launch =======================

extern "C" void kernel_launch(void* const* d_in, const int* in_sizes, int n_in,
                              void* d_out, int out_size, void* d_ws, size_t ws_size,
                              hipStream_t stream) {
    const float* x    = (const float*)d_in[0];
    const int*   ei   = (const int*)d_in[1];
    const float* W    = (const float*)d_in[2];
    const float* bias = (const float*)d_in[3];
    float* out = (float*)d_out;

    // workspace layout (bytes):
    //   [0        ..   200000)  dis / degi (fallback)
    //   [200000   ..   400064)  offs (N+1 ints)
    //   [400064   ..   600064)  offs_local / cnt (fallback)
    //   [600064   ..   800064)  cur (fallback only)
    //   [800064   ..   801088)  partials
    //   [801088   ..  4001088)  csr (800000 x int)
    //   [4001088  .. 10401088)  hs (50000 x 64 bf16)
    //   [10401088 .. 16801088)  bh (128 x 12500 u32, u8-packed)
    //   [16801088 .. 20001088)  bs8 (64 x 50000 u8, relative)
    char* ws = (char*)d_ws;
    float*          dis      = (float*)(ws + 0);
    int*            offs     = (int*)(ws + 200000);
    int*            offs_loc = (int*)(ws + 400064);
    int*            cur      = (int*)(ws + 600064);
    int*            partials = (int*)(ws + 800064);
    int*            csr      = (int*)(ws + 801088);
    unsigned short* hs       = (unsigned short*)(ws + 4001088);
    unsigned*       bh       = (unsigned*)(ws + 10401088);
    unsigned char*  bs8      = (unsigned char*)(ws + 16801088);

    const size_t WS_NEEDED = 20001088;

    if (ws_size >= WS_NEEDED) {
        hist_priv_kernel<<<2 * B_SLICE, 1024, 0, stream>>>(ei, bh);
        reduce_scan_kernel<<<NB_SCAN, 256, 0, stream>>>(bh, dis, offs_loc, partials, bs8);
        gemm_kernel<<<(N_NODES + 63) / 64, 256, 0, stream>>>(x, W, dis, hs,
                                                             offs_loc, partials, offs, 1);
        bucket_det_kernel<<<4 * B_SLICE, 1024, 0, stream>>>(ei, bs8, offs, csr);
        gather_kernel<<<(N_NODES + 3) / 4, 256, 0, stream>>>(offs, csr, hs, dis, bias, out);
    } else {
        const int* row = ei;
        const int* col = ei + N_EDGES;
        int* degi = (int*)dis;
        int* cntf = offs_loc;
        hipMemsetAsync(ws, 0, 800064, stream);
        histf_kernel<<<(N_EDGES + 255) / 256, 256, 0, stream>>>(row, col, degi, cntf);
        disf_kernel<<<(N_NODES + 255) / 256, 256, 0, stream>>>(degi);
        block_scan_kernel<<<NB_SCAN, 256, 0, stream>>>(cntf, offs, partials);
        scan_partials_kernel<<<1, 256, 0, stream>>>(partials);
        add_off_kernel<<<NB_SCAN, 256, 0, stream>>>(offs, partials);
        gemm_kernel<<<(N_NODES + 63) / 64, 256, 0, stream>>>(x, W, dis, hs,
                                                             offs_loc, partials, offs, 0);
        bucket_fb_kernel<<<(N_EDGES + 255) / 256, 256, 0, stream>>>(row, col, offs, cur, csr);
        gather_kernel<<<(N_NODES + 3) / 4, 256, 0, stream>>>(offs, csr, hs, dis, bias, out);
    }
}

// Round 8
// 127.596 us; speedup vs baseline: 2.8637x; 2.8637x over previous
//
#include <hip/hip_runtime.h>
#include <hip/hip_bf16.h>

// GCN layer: out[c] = bias + dis[c]*(hs[c] + sum_{r in in(c)} hs[r]),
//            hs = (X @ W) * dis[row]  (bf16), dis = rsqrt(deg+1).
// N=50000, E=800000, D=64, fp32 in/out.
// R22: R21 measured reduce_scan = 13.75us warm, latency-bound (HBM 1.8%,
//      VALU 3.9%, occupancy 8.4%: 196 blocks x 4 waves, 8 serial rounds of
//      16-deep strided loads). Fix: 1024-thread blocks, 4 slice-groups x 256
//      nodes -> 16 loads/phase/thread (1 MLP round), 4x waves/CU, outputs
//      bit-identical (group-base + in-group prefix == full prefix).
//      Everything else byte-identical to proven R16 (128.7us).

constexpr int N_NODES = 50000;
constexpr int N_EDGES = 800000;
constexpr int D = 64;
constexpr int NB_SCAN = (N_NODES + 255) / 256;  // 196

constexpr int B_SLICE = 64;                  // edge slices
constexpr int SLICE = N_EDGES / B_SLICE;     // 12500 (exact)
constexpr int PACK8 = N_NODES / 4;           // 12500 u32 words (u8 x4)
constexpr int QUAR = N_NODES / 4;            // 12500 nodes per bucket quarter

static __device__ __forceinline__ unsigned short f2bf(float f) {
    unsigned u = __float_as_uint(f);
    unsigned r = (u + 0x7fffu + ((u >> 16) & 1u)) >> 16;  // RNE
    return (unsigned short)r;
}
static __device__ __forceinline__ float bf2f(unsigned short s) {
    return __uint_as_float((unsigned)s << 16);
}

// ---- 1. per-slice u8-packed histograms (R12 proven) ----
__global__ __launch_bounds__(1024) void hist_priv_kernel(const int* __restrict__ ei,
                                                         unsigned* __restrict__ bh) {
    __shared__ unsigned loc[PACK8];  // 50 KB
    int b = blockIdx.x;
    int s = b & (B_SLICE - 1);
    const int* arr = (b < B_SLICE) ? ei : ei + N_EDGES;
    for (int w = threadIdx.x; w < PACK8; w += 1024) loc[w] = 0;
    __syncthreads();
    const int* p = arr + s * SLICE;
    for (int i = threadIdx.x; i < SLICE; i += 1024) {
        int k = p[i];
        atomicAdd(&loc[k >> 2], 1u << (8 * (k & 3)));  // LDS atomic, ~Poisson(.25)/bin
    }
    __syncthreads();
    unsigned* dst = bh + (size_t)b * PACK8;
    for (int w = threadIdx.x; w < PACK8; w += 1024) dst[w] = loc[w];
}

// ---- 2. reduce + dis + inline bs8 + block-local scan; R22: 1024 threads =
//         4 slice-groups x 256 nodes. Group g loads 16 row + 16 col words
//         (one 16-deep MLP round each), computes in-group prefix; LDS
//         combines group sums; outputs bit-identical to the serial form. ----
__global__ __launch_bounds__(1024) void reduce_scan_kernel(const unsigned* __restrict__ bh,
                                                           float* __restrict__ dis,
                                                           int* __restrict__ offs_local,
                                                           int* __restrict__ partials,
                                                           unsigned char* __restrict__ bs8) {
    __shared__ int degp[4][256];
    __shared__ int colp[4][256];
    __shared__ int s[256];
    const int t = threadIdx.x;
    const int nl = t & 255;   // node within block
    const int g = t >> 8;     // slice group 0..3 (slices 16g..16g+15)
    const int i = blockIdx.x * 256 + nl;

    unsigned lp[16];
    int ct = 0;
    if (i < N_NODES) {
        const int w = i >> 2;
        const unsigned sh = 8 * (i & 3);
        const unsigned* prow = bh + (size_t)(g * 16) * PACK8 + w;
        unsigned vr[16];
#pragma unroll
        for (int k = 0; k < 16; ++k) vr[k] = prow[(size_t)k * PACK8];  // 16 in flight
        int dl = 0;
#pragma unroll
        for (int k = 0; k < 16; ++k) dl += (int)((vr[k] >> sh) & 0xffu);
        degp[g][nl] = dl;

        const unsigned* pcol = bh + (size_t)(B_SLICE + g * 16) * PACK8 + w;
        unsigned vc[16];
#pragma unroll
        for (int k = 0; k < 16; ++k) vc[k] = pcol[(size_t)k * PACK8];  // 16 in flight
        unsigned c = 0;
#pragma unroll
        for (int k = 0; k < 16; ++k) { lp[k] = c; c += (vc[k] >> sh) & 0xffu; }
        ct = (int)c;
        colp[g][nl] = ct;
    } else {
        degp[g][nl] = 0;
        colp[g][nl] = 0;
    }
    __syncthreads();

    if (i < N_NODES) {
        int base = 0;
#pragma unroll
        for (int gg = 0; gg < 4; ++gg) if (gg < g) base += colp[gg][nl];
#pragma unroll
        for (int k = 0; k < 16; ++k)
            bs8[(size_t)(g * 16 + k) * N_NODES + i] = (unsigned char)(base + (int)lp[k]);
        if (g == 0) {
            int deg = degp[0][nl] + degp[1][nl] + degp[2][nl] + degp[3][nl];
            dis[i] = rsqrtf((float)deg + 1.0f);  // +1 self loop
        }
    }
    if (g == 0) s[nl] = colp[0][nl] + colp[1][nl] + colp[2][nl] + colp[3][nl];
    __syncthreads();

    // 256-wide scan, barriers uniform across all 1024 threads
    for (int d = 1; d < 256; d <<= 1) {
        int u = (t < 256 && t >= d) ? s[t - d] : 0;
        __syncthreads();
        if (t < 256) s[t] += u;
        __syncthreads();
    }
    if (g == 0 && i < N_NODES) {
        int tot = colp[0][nl] + colp[1][nl] + colp[2][nl] + colp[3][nl];
        offs_local[i] = s[nl] - tot;
    }
    if (t == 255) partials[blockIdx.x] = s[255];
}

// ---- 3. gemm: 64x64 tile, 4x4 reg tile, hs = bf16(h*dis[row]) (R12 proven)
//         + fused offs finalize: blocks < 196 scan the 196 partials (1KB LDS)
//           and write absolute offs for their 256-node chunk. ----
__global__ __launch_bounds__(256, 4) void gemm_kernel(const float* __restrict__ x,
                                                      const float* __restrict__ W,
                                                      const float* __restrict__ dis,
                                                      unsigned short* __restrict__ hs,
                                                      const int* __restrict__ offs_local,
                                                      const int* __restrict__ partials,
                                                      int* __restrict__ offs,
                                                      int do_offs) {
    __shared__ float Xs[64][68];  // pad: 2-way max bank alias = free
    __shared__ float Ws[64][64];
    __shared__ int pref[256];
    int t = threadIdx.x;
    int b = blockIdx.x;

    if (do_offs && b < NB_SCAN) {  // block-uniform branch
        pref[t] = (t < NB_SCAN) ? partials[t] : 0;
        __syncthreads();
        for (int d = 1; d < 256; d <<= 1) {
            int u = (t >= d) ? pref[t - d] : 0;
            __syncthreads();
            pref[t] += u;
            __syncthreads();
        }
        int base = pref[b] - partials[b];  // exclusive prefix of this chunk
        int node = b * 256 + t;
        if (node < N_NODES) offs[node] = base + offs_local[node];
        if (b == 0 && t == 0) offs[N_NODES] = N_EDGES;  // sentinel
        // no barrier needed: pref not reused, Xs/Ws disjoint
    }

    int n0 = blockIdx.x * 64;

    const float4* W4 = (const float4*)W;
    float4* Ws4 = (float4*)Ws;
#pragma unroll
    for (int i = 0; i < 4; ++i) Ws4[t + i * 256] = W4[t + i * 256];

    const float4* x4 = (const float4*)(x + (size_t)n0 * D);
#pragma unroll
    for (int i = 0; i < 4; ++i) {
        int f = t + i * 256;
        int r = f >> 4, c = (f & 15) << 2;
        float4 v = make_float4(0.f, 0.f, 0.f, 0.f);
        if (n0 + r < N_NODES) v = x4[f];
        Xs[r][c] = v.x; Xs[r][c + 1] = v.y; Xs[r][c + 2] = v.z; Xs[r][c + 3] = v.w;
    }
    __syncthreads();

    int tx = t & 15, ty = t >> 4;
    float acc[4][4] = {};
#pragma unroll 8
    for (int k = 0; k < D; ++k) {
        float a[4], bb[4];
#pragma unroll
        for (int i = 0; i < 4; ++i) a[i] = Xs[ty * 4 + i][k];
#pragma unroll
        for (int jj = 0; jj < 4; ++jj) bb[jj] = Ws[k][tx * 4 + jj];
#pragma unroll
        for (int i = 0; i < 4; ++i)
#pragma unroll
            for (int jj = 0; jj < 4; ++jj)
                acc[i][jj] = fmaf(a[i], bb[jj], acc[i][jj]);
    }

#pragma unroll
    for (int i = 0; i < 4; ++i) {
        int r = ty * 4 + i;
        if (n0 + r < N_NODES) {
            float dr = dis[n0 + r];
            ushort4 v;
            v.x = f2bf(acc[i][0] * dr); v.y = f2bf(acc[i][1] * dr);
            v.z = f2bf(acc[i][2] * dr); v.w = f2bf(acc[i][3] * dr);
            *(ushort4*)(hs + (size_t)(n0 + r) * D + tx * 4) = v;
        }
    }
}

// ---- 4. bucket: u8-packed LDS position counters (rel+cnt <= deg-1 <= 254).
//         pos init = raw copy of bs8 quarter-slice; abs base = offs[c] (L2-hot
//         200KB). 12.5KB LDS -> 2 blocks/CU. (R16 proven) ----
__global__ __launch_bounds__(1024) void bucket_det_kernel(const int* __restrict__ ei,
                                                          const unsigned char* __restrict__ bs8,
                                                          const int* __restrict__ offs,
                                                          int* __restrict__ csr) {
    __shared__ unsigned pos[QUAR / 4];  // 12.5 KB, u8 x4 per word
    const int t = threadIdx.x;
    const int s = blockIdx.x >> 2;
    const int q = blockIdx.x & 3;
    const int c0 = q * QUAR;

    // init: rel8 start offsets for this (slice, quarter); 50000%4==0, 12500%4==0
    const unsigned* rel32 = (const unsigned*)(bs8 + (size_t)s * N_NODES + c0);
    for (int w = t; w < QUAR / 4; w += 1024) pos[w] = rel32[w];
    __syncthreads();

    const int* rowp = ei + s * SLICE;
    const int* colp = ei + N_EDGES + s * SLICE;
    for (int i = t; i < SLICE; i += 1024) {
        int c = colp[i];
        unsigned cc = (unsigned)(c - c0);
        if (cc < (unsigned)QUAR) {
            int base = offs[c];  // issue early, independent of atomic
            unsigned old = atomicAdd(&pos[cc >> 2], 1u << (8 * (cc & 3)));
            unsigned rel = (old >> (8 * (cc & 3))) & 0xffu;
            csr[base + (int)rel] = rowp[i];
        }
    }
}

// ---- 5. gather: wave per node, scalar csr loads, MLP 16 (R12 proven) ----
__global__ __launch_bounds__(256) void gather_kernel(const int* __restrict__ offs,
                                                     const int* __restrict__ csr,
                                                     const unsigned short* __restrict__ hs,
                                                     const float* __restrict__ dis,
                                                     const float* __restrict__ bias,
                                                     float* __restrict__ out) {
    int wave = threadIdx.x >> 6;
    int j = threadIdx.x & 63;
    int n = blockIdx.x * 4 + wave;
    if (n >= N_NODES) return;

    float a[8];
    a[0] = bf2f(hs[(size_t)n * D + j]);  // self loop (dis[n]*h[n])
#pragma unroll
    for (int k = 1; k < 8; ++k) a[k] = 0.f;

    // wave-uniform (SGPR) csr addressing -> scalar loads, free broadcast
    int beg = __builtin_amdgcn_readfirstlane(offs[n]);
    int m   = __builtin_amdgcn_readfirstlane(offs[n + 1]) - beg;
    const int* p = csr + beg;

    int i = 0;
    for (; i + 16 <= m; i += 16) {
        int r[16];
        float v[16];
#pragma unroll
        for (int k = 0; k < 16; ++k) r[k] = p[i + k];
#pragma unroll
        for (int k = 0; k < 16; ++k) v[k] = bf2f(hs[(size_t)r[k] * D + j]);  // 16 in flight
#pragma unroll
        for (int k = 0; k < 16; ++k) a[k & 7] += v[k];
    }
    for (; i + 4 <= m; i += 4) {
        int r0 = p[i], r1 = p[i + 1], r2 = p[i + 2], r3 = p[i + 3];
        a[0] += bf2f(hs[(size_t)r0 * D + j]);
        a[1] += bf2f(hs[(size_t)r1 * D + j]);
        a[2] += bf2f(hs[(size_t)r2 * D + j]);
        a[3] += bf2f(hs[(size_t)r3 * D + j]);
    }
    for (; i < m; ++i) a[1] += bf2f(hs[(size_t)p[i] * D + j]);
    float tot = ((a[0] + a[1]) + (a[2] + a[3])) + ((a[4] + a[5]) + (a[6] + a[7]));
    out[(size_t)n * D + j] = fmaf(dis[n], tot, bias[j]);
}

// ======================= fallback (atomic) build path =======================

__global__ void histf_kernel(const int* __restrict__ row, const int* __restrict__ col,
                             int* __restrict__ degi, int* __restrict__ cnt) {
    int e = blockIdx.x * blockDim.x + threadIdx.x;
    if (e < N_EDGES) {
        atomicAdd(&degi[row[e]], 1);
        atomicAdd(&cnt[col[e]], 1);
    }
}

__global__ void disf_kernel(int* __restrict__ degi) {
    int i = blockIdx.x * blockDim.x + threadIdx.x;
    if (i < N_NODES) {
        float d = (float)degi[i] + 1.0f;
        ((float*)degi)[i] = rsqrtf(d);
    }
}

__global__ void block_scan_kernel(const int* __restrict__ cnt, int* __restrict__ offs,
                                  int* __restrict__ partials) {
    __shared__ int s[256];
    int t = threadIdx.x;
    int i = blockIdx.x * 256 + t;
    int v = (i < N_NODES) ? cnt[i] : 0;
    s[t] = v;
    __syncthreads();
    for (int d = 1; d < 256; d <<= 1) {
        int u = (t >= d) ? s[t - d] : 0;
        __syncthreads();
        s[t] += u;
        __syncthreads();
    }
    if (i < N_NODES) offs[i] = s[t] - v;
    if (t == 255) partials[blockIdx.x] = s[t];
}

__global__ void scan_partials_kernel(int* __restrict__ partials) {
    __shared__ int s[256];
    int t = threadIdx.x;
    int v = (t < NB_SCAN) ? partials[t] : 0;
    s[t] = v;
    __syncthreads();
    for (int d = 1; d < 256; d <<= 1) {
        int u = (t >= d) ? s[t - d] : 0;
        __syncthreads();
        s[t] += u;
        __syncthreads();
    }
    if (t < NB_SCAN) partials[t] = s[t] - v;
}

__global__ void add_off_kernel(int* __restrict__ offs, const int* __restrict__ partials) {
    int i = blockIdx.x * 256 + threadIdx.x;
    if (i < N_NODES) offs[i] += partials[blockIdx.x];
    if (i == 0) offs[N_NODES] = N_EDGES;
}

__global__ void bucket_fb_kernel(const int* __restrict__ row, const int* __restrict__ col,
                                 const int* __restrict__ offs, int* __restrict__ cur,
                                 int* __restrict__ csr) {
    int e = blockIdx.x * blockDim.x + threadIdx.x;
    if (e < N_EDGES) {
        int c = col[e];
        int pos = offs[c] + atomicAdd(&cur[c], 1);
        csr[pos] = row[e];
    }
}

// ======================= launch =======================

extern "C" void kernel_launch(void* const* d_in, const int* in_sizes, int n_in,
                              void* d_out, int out_size, void* d_ws, size_t ws_size,
                              hipStream_t stream) {
    const float* x    = (const float*)d_in[0];
    const int*   ei   = (const int*)d_in[1];
    const float* W    = (const float*)d_in[2];
    const float* bias = (const float*)d_in[3];
    float* out = (float*)d_out;

    // workspace layout (bytes):
    //   [0        ..   200000)  dis / degi (fallback)
    //   [200000   ..   400064)  offs (N+1 ints)
    //   [400064   ..   600064)  offs_local / cnt (fallback)
    //   [600064   ..   800064)  cur (fallback only)
    //   [800064   ..   801088)  partials
    //   [801088   ..  4001088)  csr (800000 x int)
    //   [4001088  .. 10401088)  hs (50000 x 64 bf16)
    //   [10401088 .. 16801088)  bh (128 x 12500 u32, u8-packed)
    //   [16801088 .. 20001088)  bs8 (64 x 50000 u8, relative)
    char* ws = (char*)d_ws;
    float*          dis      = (float*)(ws + 0);
    int*            offs     = (int*)(ws + 200000);
    int*            offs_loc = (int*)(ws + 400064);
    int*            cur      = (int*)(ws + 600064);
    int*            partials = (int*)(ws + 800064);
    int*            csr      = (int*)(ws + 801088);
    unsigned short* hs       = (unsigned short*)(ws + 4001088);
    unsigned*       bh       = (unsigned*)(ws + 10401088);
    unsigned char*  bs8      = (unsigned char*)(ws + 16801088);

    const size_t WS_NEEDED = 20001088;

    if (ws_size >= WS_NEEDED) {
        hist_priv_kernel<<<2 * B_SLICE, 1024, 0, stream>>>(ei, bh);
        reduce_scan_kernel<<<NB_SCAN, 1024, 0, stream>>>(bh, dis, offs_loc, partials, bs8);
        gemm_kernel<<<(N_NODES + 63) / 64, 256, 0, stream>>>(x, W, dis, hs,
                                                             offs_loc, partials, offs, 1);
        bucket_det_kernel<<<4 * B_SLICE, 1024, 0, stream>>>(ei, bs8, offs, csr);
        gather_kernel<<<(N_NODES + 3) / 4, 256, 0, stream>>>(offs, csr, hs, dis, bias, out);
    } else {
        const int* row = ei;
        const int* col = ei + N_EDGES;
        int* degi = (int*)dis;
        int* cntf = offs_loc;
        hipMemsetAsync(ws, 0, 800064, stream);
        histf_kernel<<<(N_EDGES + 255) / 256, 256, 0, stream>>>(row, col, degi, cntf);
        disf_kernel<<<(N_NODES + 255) / 256, 256, 0, stream>>>(degi);
        block_scan_kernel<<<NB_SCAN, 256, 0, stream>>>(cntf, offs, partials);
        scan_partials_kernel<<<1, 256, 0, stream>>>(partials);
        add_off_kernel<<<NB_SCAN, 256, 0, stream>>>(offs, partials);
        gemm_kernel<<<(N_NODES + 63) / 64, 256, 0, stream>>>(x, W, dis, hs,
                                                             offs_loc, partials, offs, 0);
        bucket_fb_kernel<<<(N_EDGES + 255) / 256, 256, 0, stream>>>(row, col, offs, cur, csr);
        gather_kernel<<<(N_NODES + 3) / 4, 256, 0, stream>>>(offs, csr, hs, dis, bias, out);
    }
}